// Round 5
// baseline (324.173 us; speedup 1.0000x reference)
//
#include <hip/hip_runtime.h>

// log-ODE Neural CDE. B=32 chains, 32 windows, Heun = 2 vector-field evals
// per window. fp32 in/out, f32 accum, f16 weights/activations (v_dot2_f32_f16).
// 512 threads/block (8 waves), one block per batch element.
//
// R13 (resubmit R14: prior bench was an infra failure, kernel re-audited --
// uniform barriers, wave-local waitcnt hand-offs, LDS bounds, DPP ctrls OK).
// Phase/latency restructure -- 5 barriers per eval (was 6), two barrier-free
// wave-local stretches. Post-mortem R12: LDS traffic shaving hit diminishing
// returns; ~800 cyc/phase is lockstep barrier+latency.
//  * A wave-local: every wave computes FULL h1 redundantly (lane: rows l,
//    l+64, full K; w1a/w1b = 64 u32). B reads a wave-private copy -> no
//    barrier between A and B, waves may slip. dp1 stays in registers.
//  * D wave-local (dir w per wave): u_w from transposed sFt[a][i] (one
//    ds_read_b128/lane) + 8 uniform C coeffs (LDS reads, replaces the big
//    per-window cJ build); D1_w rows l,l+64 REUSE w1a/w1b + in-reg dp1.
//    Zero DPP in A and D.
//  * F's final __shfl_xor(4) -> DPP row_half_mirror (quad is uniform after
//    XOR1+XOR2, so l^7 carries the l^4 value): no LDS op on y-update path.
#define NBATCH 32
#define LPATH  513
#define NWIN   32
#define LSIG   36
#define DSTR   136   // [dir] stride sD1/sD2 (f16) = 17 uint4

typedef unsigned int u32;
typedef _Float16 h2 __attribute__((ext_vector_type(2)));

__device__ __forceinline__ u32 pkh(float a, float b){
  return __builtin_bit_cast(u32, __builtin_amdgcn_cvt_pkrtz(a, b));
}
__device__ __forceinline__ float dot2(u32 a, u32 b, float c){
#if __has_builtin(__builtin_amdgcn_fdot2)
  return __builtin_amdgcn_fdot2(__builtin_bit_cast(h2,a),
                                __builtin_bit_cast(h2,b), c, false);
#else
  h2 x = __builtin_bit_cast(h2,a), y = __builtin_bit_cast(h2,b);
  return c + (float)x[0]*(float)y[0] + (float)x[1]*(float)y[1];
#endif
}
__device__ __forceinline__ float tanh_fast(float x){
  float e = __expf(2.f*x);
  return 1.f - 2.f/(e+1.f);
}

// DPP cross-lane adds: VALU-only, no LDS-pipe traffic.
#define DPP_XOR1 0xB1   // quad_perm [1,0,3,2]
#define DPP_XOR2 0x4E   // quad_perm [2,3,0,1]
#define DPP_ROR8 0x128  // row_ror:8 == lane^8 within each 16-lane row
#define DPP_HMIR 0x141  // row_half_mirror == lane^7 within each 8-lane half
template<int CTRL>
__device__ __forceinline__ float dppadd(float x){
  int v = __builtin_amdgcn_update_dpp(0, __builtin_bit_cast(int,x),
                                      CTRL, 0xF, 0xF, false);
  return x + __builtin_bit_cast(float, v);
}

extern "C" __global__ __launch_bounds__(512, 1)
void cde_kernel(const float* __restrict__ cv,
                const float* __restrict__ Wi1g, const float* __restrict__ bi1g,
                const float* __restrict__ Wi2g, const float* __restrict__ bi2g,
                const float* __restrict__ W1g,  const float* __restrict__ b1g,
                const float* __restrict__ W2g,  const float* __restrict__ b2g,
                const float* __restrict__ W3g,  const float* __restrict__ b3g,
                const float* __restrict__ Wrg,  const float* __restrict__ brg,
                const float* __restrict__ shg,
                float* __restrict__ outp)
{
  // ---- LDS (~15 KB) ----
  __shared__ __align__(16) float sG[NWIN*LSIG];
  __shared__ __align__(16) float sWr[256];
  __shared__ float sBr[4], sSh[1];
  __shared__ __align__(16) float sY[64];
  __shared__ float sK1[64], sLw[64];
  __shared__ __align__(16) _Float16 sYinp[64];
  __shared__ __align__(16) _Float16 sH1w[8*128];  // wave-private h1 copies
  __shared__ __align__(16) _Float16 sH2[128];
  __shared__ __align__(16) _Float16 sFt[64*8];    // f transposed: [a][i]
  __shared__ __align__(16) _Float16 sUw[8*64];    // wave-private u_w
  __shared__ __align__(16) _Float16 sD1[8*DSTR];
  __shared__ __align__(16) _Float16 sD2[8*DSTR];

  const int t  = threadIdx.x;        // 0..511
  const int b  = blockIdx.x;
  const int wv = t >> 6;             // wave id 0..7 (= dir in phase D)
  const int l  = t & 63;             // lane id
  const int r  = t >> 2;             // 0..127 (B/E row)
  const int m  = t & 1;              // col half
  const int g  = (t >> 1) & 1;       // dir group (E: 4 dirs each)
  const int hb = (t >> 3) & 1;       // bit3: pair K-slice selector
  const int i8 = t & 7;              // dir (C/F row-block)
  const int a8 = t >> 3;             // 0..63 (C/F col within block)
  const int p  = i8*64 + a8;         // owned W3 row
  const int pE = i8*64 + (a8 & ~1);  // C/F pair's even row
  const int pO = i8*64 + (a8 |  1);  // C/F pair's odd row
  const int rE = r & ~2;             // B/E pair's even row
  const int rO = r |  2;             // B/E pair's odd row

  // ---- init readout consts ----
  if (t < 256) sWr[t] = Wrg[t];
  if (t < 4)   sBr[t] = brg[t];
  if (t == 0)  sSh[0] = shg[0];

  // ---- depth-2 Lyndon log-signatures, one window per thread (t<32) ----
  if (t < NWIN){
    const float4* cv4 = (const float4*)cv;
    const int base = (b*LPATH + t*16)*2;
    float cur[8], pre[8], acc[8], lvw[28];
    { float4 a = cv4[base], d = cv4[base+1];
      cur[0]=a.x;cur[1]=a.y;cur[2]=a.z;cur[3]=a.w;
      cur[4]=d.x;cur[5]=d.y;cur[6]=d.z;cur[7]=d.w; }
    #pragma unroll
    for (int d=0; d<8; d++){ pre[d]=0.f; acc[d]=0.f; }
    #pragma unroll
    for (int pq=0; pq<28; pq++) lvw[pq]=0.f;
    for (int w=1; w<=16; w++){
      float nxt[8], inc[8];
      { float4 a = cv4[base+2*w], d = cv4[base+2*w+1];
        nxt[0]=a.x;nxt[1]=a.y;nxt[2]=a.z;nxt[3]=a.w;
        nxt[4]=d.x;nxt[5]=d.y;nxt[6]=d.z;nxt[7]=d.w; }
      #pragma unroll
      for (int d=0; d<8; d++) inc[d] = nxt[d]-cur[d];
      int pq=0;
      #pragma unroll
      for (int i=0; i<8; i++)
        #pragma unroll
        for (int j2=i+1; j2<8; j2++){ lvw[pq] += pre[i]*inc[j2] - pre[j2]*inc[i]; pq++; }
      #pragma unroll
      for (int d=0; d<8; d++){ acc[d]+=inc[d]; pre[d]+=inc[d]; cur[d]=nxt[d]; }
    }
    float* gd = &sG[t*LSIG];
    #pragma unroll
    for (int d=0; d<8; d++) gd[d] = acc[d];
    #pragma unroll
    for (int pq=0; pq<28; pq++) gd[8+pq] = 0.5f*lvw[pq];
  }

  // ---- y0 = Wi2 @ lipswish(Wi1 @ x0 + bi1) + bi2 ----
  if (t < 64){
    float z = bi1g[t];
    #pragma unroll
    for (int d=0; d<8; d++) z += Wi1g[t*8+d] * cv[(b*LPATH)*8 + d];
    float s = 1.f/(1.f+__expf(-z));
    sLw[t] = 0.909f*z*s;
  }
  __syncthreads();
  if (t < 64){
    float z = bi2g[t];
    #pragma unroll 8
    for (int k=0; k<64; k++) z += Wi2g[t*64+k] * sLw[k];
    sY[t] = z;
    sYinp[t] = (_Float16)z;
  }
  __syncthreads();
  if (t < 4){
    float z = sBr[t] + sSh[0];
    #pragma unroll 8
    for (int a=0; a<64; a++) z += sWr[t*64+a]*sY[a];
    outp[(b*33 + 0)*4 + t] = z;
  }

  // ---- per-thread weight registers ----
  // w1a/w1b: FULL W1 rows l and l+64 (A and D wave-local matvecs).
  // w2h: W2 rows rE/rO, (m,hb) K-slice (B and E, R12 layout).
  // w3e/w3o: K-half (a8&1) of rows pE/pO (C/F pair-split).
  u32 w1a[32], w1b[32], w2h[32], w3e[32], w3o[32];
  {
    const float2* W1f2 = (const float2*)W1g;
    #pragma unroll
    for (int i=0; i<32; i++){ float2 v = W1f2[l*32 + i];      w1a[i] = pkh(v.x, v.y); }
    #pragma unroll
    for (int i=0; i<32; i++){ float2 v = W1f2[(l+64)*32 + i]; w1b[i] = pkh(v.x, v.y); }
    const float2* W2f2 = (const float2*)W2g;
    #pragma unroll
    for (int i=0; i<16; i++){ float2 v = W2f2[rE*64 + m*32 + hb*16 + i]; w2h[i]    = pkh(v.x, v.y); }
    #pragma unroll
    for (int i=0; i<16; i++){ float2 v = W2f2[rO*64 + m*32 + hb*16 + i]; w2h[16+i] = pkh(v.x, v.y); }
    const float4* W3f4 = (const float4*)W3g;
    #pragma unroll
    for (int k=0; k<16; k++){
      float4 v = W3f4[pE*32 + (a8&1)*16 + k];
      w3e[2*k]   = pkh(v.x, v.y);
      w3e[2*k+1] = pkh(v.z, v.w);
    }
    #pragma unroll
    for (int k=0; k<16; k++){
      float4 v = W3f4[pO*32 + (a8&1)*16 + k];
      w3o[2*k]   = pkh(v.x, v.y);
      w3o[2*k+1] = pkh(v.z, v.w);
    }
  }
  const float b1lo = b1g[l], b1hi = b1g[l+64], b2r = b2g[r], b3r = b3g[p];

  float gi = 0.f;       // gcur[i8], per window
  float cw[8];          // C[wv][i] for this wave's dir, per window

  // One vector-field eval. mode 0: k1 (sK1, sYinp=y+k1, fused readout in A).
  // mode 1: k2 (Heun update fused in F).
  auto EVAL = [&](int mode, int s){
    __syncthreads();                          // sYinp (and sY) ready
    float dp1a, dp1b, dp2, fr;
    // ---- A (wave-local, no barrier): h1 rows l, l+64 full-K per lane ----
    {
      if (mode == 0 && s > 0 && t >= 504 && t < 508){
        int o = t - 504;
        float z = sBr[o] + sSh[0];
        const float4* wr4 = (const float4*)&sWr[o*64];
        const float4* y4f = (const float4*)sY;
        #pragma unroll
        for (int q=0; q<16; q++){
          float4 w = wr4[q], y = y4f[q];
          z += w.x*y.x + w.y*y.y + w.z*y.z + w.w*y.w;
        }
        outp[(b*33 + s)*4 + o] = z;
      }
      const uint4* y4 = (const uint4*)sYinp;  // 8 uint4, broadcast
      float a0=0.f, a1=0.f, c0=0.f, c1=0.f;
      #pragma unroll
      for (int q=0; q<8; q++){
        uint4 v = y4[q];
        a0 = dot2(w1a[4*q+0], v.x, a0); a1 = dot2(w1a[4*q+1], v.y, a1);
        a0 = dot2(w1a[4*q+2], v.z, a0); a1 = dot2(w1a[4*q+3], v.w, a1);
        c0 = dot2(w1b[4*q+0], v.x, c0); c1 = dot2(w1b[4*q+1], v.y, c1);
        c0 = dot2(w1b[4*q+2], v.z, c0); c1 = dot2(w1b[4*q+3], v.w, c1);
      }
      float za = a0 + a1 + b1lo;
      float zb = c0 + c1 + b1hi;
      float sa = 1.f/(1.f+__expf(-za));
      float sb = 1.f/(1.f+__expf(-zb));
      dp1a = 0.909f*sa*(1.f + za*(1.f-sa));
      dp1b = 0.909f*sb*(1.f + zb*(1.f-sb));
      sH1w[wv*128 + l]      = (_Float16)(0.909f*za*sa);
      sH1w[wv*128 + 64 + l] = (_Float16)(0.909f*zb*sb);
    }
    asm volatile("s_waitcnt lgkmcnt(0)" ::: "memory");
    // ---- B: h2 = lipswish(W2 h1 + b2); pair rows, (m,hb) slice ----
    {
      const uint4* h4 = (const uint4*)&sH1w[wv*128];
      const int qb = m*8 + hb*4;
      float e0=0.f, e1=0.f, o0=0.f, o1=0.f;
      #pragma unroll
      for (int q=0; q<4; q++){
        uint4 v = h4[qb + q];
        e0 = dot2(w2h[4*q+0], v.x, e0); e1 = dot2(w2h[4*q+1], v.y, e1);
        e0 = dot2(w2h[4*q+2], v.z, e0); e1 = dot2(w2h[4*q+3], v.w, e1);
        o0 = dot2(w2h[16+4*q+0], v.x, o0); o1 = dot2(w2h[16+4*q+1], v.y, o1);
        o0 = dot2(w2h[16+4*q+2], v.z, o0); o1 = dot2(w2h[16+4*q+3], v.w, o1);
      }
      float zE = dppadd<DPP_ROR8>(e0+e1);
      float zO = dppadd<DPP_ROR8>(o0+o1);
      zE = dppadd<DPP_XOR1>(zE);
      zO = dppadd<DPP_XOR1>(zO);
      float z = (hb ? zO : zE) + b2r;
      float sg = 1.f/(1.f+__expf(-z));
      dp2 = 0.909f*sg*(1.f + z*(1.f-sg));
      if ((t & 3) == 0) sH2[r] = (_Float16)(0.909f*z*sg);
    }
    __syncthreads();
    // ---- C: f = tanh(W3 h2 + b3); pair-split K-halves; write sFt[a][i] ----
    {
      const uint4* h4 = (const uint4*)sH2;
      float e0=0.f, e1=0.f, o0=0.f, o1=0.f;
      #pragma unroll
      for (int q=0; q<8; q++){
        uint4 hv = h4[(a8&1)*8 + q];          // own K-half only (8 uint4)
        e0 = dot2(w3e[4*q+0], hv.x, e0); e1 = dot2(w3e[4*q+1], hv.y, e1);
        e0 = dot2(w3e[4*q+2], hv.z, e0); e1 = dot2(w3e[4*q+3], hv.w, e1);
        o0 = dot2(w3o[4*q+0], hv.x, o0); o1 = dot2(w3o[4*q+1], hv.y, o1);
        o0 = dot2(w3o[4*q+2], hv.z, o0); o1 = dot2(w3o[4*q+3], hv.w, o1);
      }
      float se = dppadd<DPP_ROR8>(e0+e1);     // + partner's other-half partial
      float so = dppadd<DPP_ROR8>(o0+o1);
      fr = tanh_fast(((a8&1) ? so : se) + b3r);
      sFt[a8*8 + i8] = (_Float16)fr;          // transposed for D's b128 read
    }
    __syncthreads();
    // ---- D (wave-local, dir wv): u_w = sum_i C[wv,i] f_i;
    //      D1_wv = dp1 * (W1 @ u_w), rows l and l+64 via w1a/w1b ----
    {
      uint4 fv = *(const uint4*)&sFt[l*8];    // f_0..7[l], conflict-free
      h2 f01 = __builtin_bit_cast(h2, fv.x);
      h2 f23 = __builtin_bit_cast(h2, fv.y);
      h2 f45 = __builtin_bit_cast(h2, fv.z);
      h2 f67 = __builtin_bit_cast(h2, fv.w);
      float u = cw[0]*(float)f01[0] + cw[1]*(float)f01[1]
              + cw[2]*(float)f23[0] + cw[3]*(float)f23[1]
              + cw[4]*(float)f45[0] + cw[5]*(float)f45[1]
              + cw[6]*(float)f67[0] + cw[7]*(float)f67[1];
      sUw[wv*64 + l] = (_Float16)u;
      asm volatile("s_waitcnt lgkmcnt(0)" ::: "memory");
      const uint4* u4 = (const uint4*)&sUw[wv*64];  // 8 uint4, broadcast
      float a0=0.f, a1=0.f, c0=0.f, c1=0.f;
      #pragma unroll
      for (int q=0; q<8; q++){
        uint4 v = u4[q];
        a0 = dot2(w1a[4*q+0], v.x, a0); a1 = dot2(w1a[4*q+1], v.y, a1);
        a0 = dot2(w1a[4*q+2], v.z, a0); a1 = dot2(w1a[4*q+3], v.w, a1);
        c0 = dot2(w1b[4*q+0], v.x, c0); c1 = dot2(w1b[4*q+1], v.y, c1);
        c0 = dot2(w1b[4*q+2], v.z, c0); c1 = dot2(w1b[4*q+3], v.w, c1);
      }
      sD1[wv*DSTR + l]      = (_Float16)(dp1a*(a0+a1));
      sD1[wv*DSTR + 64 + l] = (_Float16)(dp1b*(c0+c1));
    }
    __syncthreads();
    // ---- E: D2_j = dp2 * (W2 @ D1_j); pair rows, (m,hb) slice ----
    {
      const uint4* d4 = (const uint4*)sD1;
      #pragma unroll
      for (int k=0; k<4; k++){
        const int dir = 4*g + k;
        const uint4* dd = &d4[dir*17 + m*8 + hb*4];
        float e0=0.f, e1=0.f, o0=0.f, o1=0.f;
        #pragma unroll
        for (int q=0; q<4; q++){
          uint4 v = dd[q];
          e0 = dot2(w2h[4*q+0], v.x, e0); e1 = dot2(w2h[4*q+1], v.y, e1);
          e0 = dot2(w2h[4*q+2], v.z, e0); e1 = dot2(w2h[4*q+3], v.w, e1);
          o0 = dot2(w2h[16+4*q+0], v.x, o0); o1 = dot2(w2h[16+4*q+1], v.y, o1);
          o0 = dot2(w2h[16+4*q+2], v.z, o0); o1 = dot2(w2h[16+4*q+3], v.w, o1);
        }
        float zE = dppadd<DPP_ROR8>(e0+e1);
        float zO = dppadd<DPP_ROR8>(o0+o1);
        zE = dppadd<DPP_XOR1>(zE);
        zO = dppadd<DPP_XOR1>(zO);
        float z = hb ? zO : zE;               // own row
        if (m == 0) sD2[dir*DSTR + r] = (_Float16)(dp2*z);
      }
    }
    __syncthreads();
    // ---- F: con = g_i*f + (1-f^2)*(W3 D2_i); k-sum all-DPP; Heun fused ----
    {
      const uint4* d4 = (const uint4*)&sD2[i8*DSTR];
      float e0=0.f, e1=0.f, o0=0.f, o1=0.f;
      #pragma unroll
      for (int q=0; q<8; q++){
        uint4 dv = d4[(a8&1)*8 + q];          // own K-half of D2[i8]
        e0 = dot2(w3e[4*q+0], dv.x, e0); e1 = dot2(w3e[4*q+1], dv.y, e1);
        e0 = dot2(w3e[4*q+2], dv.z, e0); e1 = dot2(w3e[4*q+3], dv.w, e1);
        o0 = dot2(w3o[4*q+0], dv.x, o0); o1 = dot2(w3o[4*q+1], dv.y, o1);
        o0 = dot2(w3o[4*q+2], dv.z, o0); o1 = dot2(w3o[4*q+3], dv.w, o1);
      }
      float ze = dppadd<DPP_ROR8>(e0+e1);
      float zo = dppadd<DPP_ROR8>(o0+o1);
      float z  = (a8&1) ? zo : ze;
      float con = gi*fr + (1.f - fr*fr)*z;
      con = dppadd<DPP_XOR1>(con);            // i8 bit0
      con = dppadd<DPP_XOR2>(con);            // i8 bit1
      con = dppadd<DPP_HMIR>(con);            // i8 bit2 (quad uniform -> l^7 ok)
      if (i8 == 0){
        if (mode == 0){
          sK1[a8] = con;
          sYinp[a8] = (_Float16)(sY[a8] + con);   // midpoint input for eval2
        } else {
          float yn = sY[a8] + 0.5f*(sK1[a8] + con);
          sY[a8] = yn;
          sYinp[a8] = (_Float16)yn;
        }
      }
    }
  };

  // ---- main scan over windows ----
  for (int s = 0; s < NWIN; s++){
    const float* gcur = &sG[s*LSIG];
    gi = gcur[i8];
    // C[wv][i] for this wave's dir (8 uniform LDS reads, per window).
    #pragma unroll
    for (int i=0; i<8; i++){
      if (i == wv) cw[i] = 0.f;
      else {
        int lo = i < wv ? i : wv, hi = i < wv ? wv : i;
        float v = gcur[8 + 7*lo - (lo*(lo-1))/2 + (hi-lo-1)];
        cw[i] = (i < wv) ? v : -v;
      }
    }
    EVAL(0, s);
    EVAL(1, s);
  }
  __syncthreads();
  if (t < 4){                                 // final readout (y after win 31)
    float z = sBr[t] + sSh[0];
    #pragma unroll 8
    for (int a=0; a<64; a++) z += sWr[t*64+a]*sY[a];
    outp[(b*33 + 32)*4 + t] = z;
  }
}

extern "C" void kernel_launch(void* const* d_in, const int* in_sizes, int n_in,
                              void* d_out, int out_size, void* d_ws, size_t ws_size,
                              hipStream_t stream) {
  cde_kernel<<<dim3(NBATCH), dim3(512), 0, stream>>>(
      (const float*)d_in[0],
      (const float*)d_in[1],  (const float*)d_in[2],
      (const float*)d_in[3],  (const float*)d_in[4],
      (const float*)d_in[5],  (const float*)d_in[6],
      (const float*)d_in[7],  (const float*)d_in[8],
      (const float*)d_in[9],  (const float*)d_in[10],
      (const float*)d_in[11], (const float*)d_in[12],
      (const float*)d_in[13],
      (float*)d_out);
}

// Round 6
// 323.507 us; speedup vs baseline: 1.0021x; 1.0021x over previous
//
#include <hip/hip_runtime.h>

// log-ODE Neural CDE. B=32 chains, 32 windows, Heun = 2 vector-field evals
// per window. fp32 in/out, f32 accum, f16 weights/activations (v_dot2_f32_f16).
// 512 threads/block (8 waves), one block per batch element.
//
// R15 = R13 structure + amdgpu_waves_per_eu(2,2).
// Post-mortem R13/R14: correct but spilled -- 160 weight u32/lane vs the
// compiler's 128-VGPR occupancy target (VGPR_Count=128, WRITE_SIZE 17->1673KB
// = scratch). Real occupancy is fixed at 2 waves/SIMD (32 blocks, 1/CU), so
// occupancy above 2/EU is waste: waves_per_eu(2,2) lifts the cap to 256 VGPR
// -> ~200-reg working set fits, zero spill.
// R13 structure: 5 barriers/eval, two barrier-free wave-local stretches:
//  * A wave-local: every wave computes FULL h1 redundantly (lane: rows l,
//    l+64, full K; w1a/w1b = 64 u32). B reads a wave-private copy.
//  * D wave-local (dir w per wave): u_w from transposed sFt[a][i] + 8
//    uniform C coeffs; D1_w rows l,l+64 reuse w1a/w1b + in-reg dp1.
//  * F's k-sum all-DPP (XOR1, XOR2, row_half_mirror for bit2).
#define NBATCH 32
#define LPATH  513
#define NWIN   32
#define LSIG   36
#define DSTR   136   // [dir] stride sD1/sD2 (f16) = 17 uint4

typedef unsigned int u32;
typedef _Float16 h2 __attribute__((ext_vector_type(2)));

__device__ __forceinline__ u32 pkh(float a, float b){
  return __builtin_bit_cast(u32, __builtin_amdgcn_cvt_pkrtz(a, b));
}
__device__ __forceinline__ float dot2(u32 a, u32 b, float c){
#if __has_builtin(__builtin_amdgcn_fdot2)
  return __builtin_amdgcn_fdot2(__builtin_bit_cast(h2,a),
                                __builtin_bit_cast(h2,b), c, false);
#else
  h2 x = __builtin_bit_cast(h2,a), y = __builtin_bit_cast(h2,b);
  return c + (float)x[0]*(float)y[0] + (float)x[1]*(float)y[1];
#endif
}
__device__ __forceinline__ float tanh_fast(float x){
  float e = __expf(2.f*x);
  return 1.f - 2.f/(e+1.f);
}

// DPP cross-lane adds: VALU-only, no LDS-pipe traffic.
#define DPP_XOR1 0xB1   // quad_perm [1,0,3,2]
#define DPP_XOR2 0x4E   // quad_perm [2,3,0,1]
#define DPP_ROR8 0x128  // row_ror:8 == lane^8 within each 16-lane row
#define DPP_HMIR 0x141  // row_half_mirror == lane^7 within each 8-lane half
template<int CTRL>
__device__ __forceinline__ float dppadd(float x){
  int v = __builtin_amdgcn_update_dpp(0, __builtin_bit_cast(int,x),
                                      CTRL, 0xF, 0xF, false);
  return x + __builtin_bit_cast(float, v);
}

extern "C" __global__ __launch_bounds__(512)
__attribute__((amdgpu_waves_per_eu(2, 2)))
void cde_kernel(const float* __restrict__ cv,
                const float* __restrict__ Wi1g, const float* __restrict__ bi1g,
                const float* __restrict__ Wi2g, const float* __restrict__ bi2g,
                const float* __restrict__ W1g,  const float* __restrict__ b1g,
                const float* __restrict__ W2g,  const float* __restrict__ b2g,
                const float* __restrict__ W3g,  const float* __restrict__ b3g,
                const float* __restrict__ Wrg,  const float* __restrict__ brg,
                const float* __restrict__ shg,
                float* __restrict__ outp)
{
  // ---- LDS (~15 KB) ----
  __shared__ __align__(16) float sG[NWIN*LSIG];
  __shared__ __align__(16) float sWr[256];
  __shared__ float sBr[4], sSh[1];
  __shared__ __align__(16) float sY[64];
  __shared__ float sK1[64], sLw[64];
  __shared__ __align__(16) _Float16 sYinp[64];
  __shared__ __align__(16) _Float16 sH1w[8*128];  // wave-private h1 copies
  __shared__ __align__(16) _Float16 sH2[128];
  __shared__ __align__(16) _Float16 sFt[64*8];    // f transposed: [a][i]
  __shared__ __align__(16) _Float16 sUw[8*64];    // wave-private u_w
  __shared__ __align__(16) _Float16 sD1[8*DSTR];
  __shared__ __align__(16) _Float16 sD2[8*DSTR];

  const int t  = threadIdx.x;        // 0..511
  const int b  = blockIdx.x;
  const int wv = t >> 6;             // wave id 0..7 (= dir in phase D)
  const int l  = t & 63;             // lane id
  const int r  = t >> 2;             // 0..127 (B/E row)
  const int m  = t & 1;              // col half
  const int g  = (t >> 1) & 1;       // dir group (E: 4 dirs each)
  const int hb = (t >> 3) & 1;       // bit3: pair K-slice selector
  const int i8 = t & 7;              // dir (C/F row-block)
  const int a8 = t >> 3;             // 0..63 (C/F col within block)
  const int p  = i8*64 + a8;         // owned W3 row
  const int pE = i8*64 + (a8 & ~1);  // C/F pair's even row
  const int pO = i8*64 + (a8 |  1);  // C/F pair's odd row
  const int rE = r & ~2;             // B/E pair's even row
  const int rO = r |  2;             // B/E pair's odd row

  // ---- init readout consts ----
  if (t < 256) sWr[t] = Wrg[t];
  if (t < 4)   sBr[t] = brg[t];
  if (t == 0)  sSh[0] = shg[0];

  // ---- depth-2 Lyndon log-signatures, one window per thread (t<32) ----
  if (t < NWIN){
    const float4* cv4 = (const float4*)cv;
    const int base = (b*LPATH + t*16)*2;
    float cur[8], pre[8], acc[8], lvw[28];
    { float4 a = cv4[base], d = cv4[base+1];
      cur[0]=a.x;cur[1]=a.y;cur[2]=a.z;cur[3]=a.w;
      cur[4]=d.x;cur[5]=d.y;cur[6]=d.z;cur[7]=d.w; }
    #pragma unroll
    for (int d=0; d<8; d++){ pre[d]=0.f; acc[d]=0.f; }
    #pragma unroll
    for (int pq=0; pq<28; pq++) lvw[pq]=0.f;
    for (int w=1; w<=16; w++){
      float nxt[8], inc[8];
      { float4 a = cv4[base+2*w], d = cv4[base+2*w+1];
        nxt[0]=a.x;nxt[1]=a.y;nxt[2]=a.z;nxt[3]=a.w;
        nxt[4]=d.x;nxt[5]=d.y;nxt[6]=d.z;nxt[7]=d.w; }
      #pragma unroll
      for (int d=0; d<8; d++) inc[d] = nxt[d]-cur[d];
      int pq=0;
      #pragma unroll
      for (int i=0; i<8; i++)
        #pragma unroll
        for (int j2=i+1; j2<8; j2++){ lvw[pq] += pre[i]*inc[j2] - pre[j2]*inc[i]; pq++; }
      #pragma unroll
      for (int d=0; d<8; d++){ acc[d]+=inc[d]; pre[d]+=inc[d]; cur[d]=nxt[d]; }
    }
    float* gd = &sG[t*LSIG];
    #pragma unroll
    for (int d=0; d<8; d++) gd[d] = acc[d];
    #pragma unroll
    for (int pq=0; pq<28; pq++) gd[8+pq] = 0.5f*lvw[pq];
  }

  // ---- y0 = Wi2 @ lipswish(Wi1 @ x0 + bi1) + bi2 ----
  if (t < 64){
    float z = bi1g[t];
    #pragma unroll
    for (int d=0; d<8; d++) z += Wi1g[t*8+d] * cv[(b*LPATH)*8 + d];
    float s = 1.f/(1.f+__expf(-z));
    sLw[t] = 0.909f*z*s;
  }
  __syncthreads();
  if (t < 64){
    float z = bi2g[t];
    #pragma unroll 8
    for (int k=0; k<64; k++) z += Wi2g[t*64+k] * sLw[k];
    sY[t] = z;
    sYinp[t] = (_Float16)z;
  }
  __syncthreads();
  if (t < 4){
    float z = sBr[t] + sSh[0];
    #pragma unroll 8
    for (int a=0; a<64; a++) z += sWr[t*64+a]*sY[a];
    outp[(b*33 + 0)*4 + t] = z;
  }

  // ---- per-thread weight registers ----
  // w1a/w1b: FULL W1 rows l and l+64 (A and D wave-local matvecs).
  // w2h: W2 rows rE/rO, (m,hb) K-slice (B and E, R12 layout).
  // w3e/w3o: K-half (a8&1) of rows pE/pO (C/F pair-split).
  u32 w1a[32], w1b[32], w2h[32], w3e[32], w3o[32];
  {
    const float2* W1f2 = (const float2*)W1g;
    #pragma unroll
    for (int i=0; i<32; i++){ float2 v = W1f2[l*32 + i];      w1a[i] = pkh(v.x, v.y); }
    #pragma unroll
    for (int i=0; i<32; i++){ float2 v = W1f2[(l+64)*32 + i]; w1b[i] = pkh(v.x, v.y); }
    const float2* W2f2 = (const float2*)W2g;
    #pragma unroll
    for (int i=0; i<16; i++){ float2 v = W2f2[rE*64 + m*32 + hb*16 + i]; w2h[i]    = pkh(v.x, v.y); }
    #pragma unroll
    for (int i=0; i<16; i++){ float2 v = W2f2[rO*64 + m*32 + hb*16 + i]; w2h[16+i] = pkh(v.x, v.y); }
    const float4* W3f4 = (const float4*)W3g;
    #pragma unroll
    for (int k=0; k<16; k++){
      float4 v = W3f4[pE*32 + (a8&1)*16 + k];
      w3e[2*k]   = pkh(v.x, v.y);
      w3e[2*k+1] = pkh(v.z, v.w);
    }
    #pragma unroll
    for (int k=0; k<16; k++){
      float4 v = W3f4[pO*32 + (a8&1)*16 + k];
      w3o[2*k]   = pkh(v.x, v.y);
      w3o[2*k+1] = pkh(v.z, v.w);
    }
  }
  const float b1lo = b1g[l], b1hi = b1g[l+64], b2r = b2g[r], b3r = b3g[p];

  float gi = 0.f;       // gcur[i8], per window
  float cw[8];          // C[wv][i] for this wave's dir, per window

  // One vector-field eval. mode 0: k1 (sK1, sYinp=y+k1, fused readout in A).
  // mode 1: k2 (Heun update fused in F).
  auto EVAL = [&](int mode, int s){
    __syncthreads();                          // sYinp (and sY) ready
    float dp1a, dp1b, dp2, fr;
    // ---- A (wave-local, no barrier): h1 rows l, l+64 full-K per lane ----
    {
      if (mode == 0 && s > 0 && t >= 504 && t < 508){
        int o = t - 504;
        float z = sBr[o] + sSh[0];
        const float4* wr4 = (const float4*)&sWr[o*64];
        const float4* y4f = (const float4*)sY;
        #pragma unroll
        for (int q=0; q<16; q++){
          float4 w = wr4[q], y = y4f[q];
          z += w.x*y.x + w.y*y.y + w.z*y.z + w.w*y.w;
        }
        outp[(b*33 + s)*4 + o] = z;
      }
      const uint4* y4 = (const uint4*)sYinp;  // 8 uint4, broadcast
      float a0=0.f, a1=0.f, c0=0.f, c1=0.f;
      #pragma unroll
      for (int q=0; q<8; q++){
        uint4 v = y4[q];
        a0 = dot2(w1a[4*q+0], v.x, a0); a1 = dot2(w1a[4*q+1], v.y, a1);
        a0 = dot2(w1a[4*q+2], v.z, a0); a1 = dot2(w1a[4*q+3], v.w, a1);
        c0 = dot2(w1b[4*q+0], v.x, c0); c1 = dot2(w1b[4*q+1], v.y, c1);
        c0 = dot2(w1b[4*q+2], v.z, c0); c1 = dot2(w1b[4*q+3], v.w, c1);
      }
      float za = a0 + a1 + b1lo;
      float zb = c0 + c1 + b1hi;
      float sa = 1.f/(1.f+__expf(-za));
      float sb = 1.f/(1.f+__expf(-zb));
      dp1a = 0.909f*sa*(1.f + za*(1.f-sa));
      dp1b = 0.909f*sb*(1.f + zb*(1.f-sb));
      sH1w[wv*128 + l]      = (_Float16)(0.909f*za*sa);
      sH1w[wv*128 + 64 + l] = (_Float16)(0.909f*zb*sb);
    }
    asm volatile("s_waitcnt lgkmcnt(0)" ::: "memory");
    // ---- B: h2 = lipswish(W2 h1 + b2); pair rows, (m,hb) slice ----
    {
      const uint4* h4 = (const uint4*)&sH1w[wv*128];
      const int qb = m*8 + hb*4;
      float e0=0.f, e1=0.f, o0=0.f, o1=0.f;
      #pragma unroll
      for (int q=0; q<4; q++){
        uint4 v = h4[qb + q];
        e0 = dot2(w2h[4*q+0], v.x, e0); e1 = dot2(w2h[4*q+1], v.y, e1);
        e0 = dot2(w2h[4*q+2], v.z, e0); e1 = dot2(w2h[4*q+3], v.w, e1);
        o0 = dot2(w2h[16+4*q+0], v.x, o0); o1 = dot2(w2h[16+4*q+1], v.y, o1);
        o0 = dot2(w2h[16+4*q+2], v.z, o0); o1 = dot2(w2h[16+4*q+3], v.w, o1);
      }
      float zE = dppadd<DPP_ROR8>(e0+e1);
      float zO = dppadd<DPP_ROR8>(o0+o1);
      zE = dppadd<DPP_XOR1>(zE);
      zO = dppadd<DPP_XOR1>(zO);
      float z = (hb ? zO : zE) + b2r;
      float sg = 1.f/(1.f+__expf(-z));
      dp2 = 0.909f*sg*(1.f + z*(1.f-sg));
      if ((t & 3) == 0) sH2[r] = (_Float16)(0.909f*z*sg);
    }
    __syncthreads();
    // ---- C: f = tanh(W3 h2 + b3); pair-split K-halves; write sFt[a][i] ----
    {
      const uint4* h4 = (const uint4*)sH2;
      float e0=0.f, e1=0.f, o0=0.f, o1=0.f;
      #pragma unroll
      for (int q=0; q<8; q++){
        uint4 hv = h4[(a8&1)*8 + q];          // own K-half only (8 uint4)
        e0 = dot2(w3e[4*q+0], hv.x, e0); e1 = dot2(w3e[4*q+1], hv.y, e1);
        e0 = dot2(w3e[4*q+2], hv.z, e0); e1 = dot2(w3e[4*q+3], hv.w, e1);
        o0 = dot2(w3o[4*q+0], hv.x, o0); o1 = dot2(w3o[4*q+1], hv.y, o1);
        o0 = dot2(w3o[4*q+2], hv.z, o0); o1 = dot2(w3o[4*q+3], hv.w, o1);
      }
      float se = dppadd<DPP_ROR8>(e0+e1);     // + partner's other-half partial
      float so = dppadd<DPP_ROR8>(o0+o1);
      fr = tanh_fast(((a8&1) ? so : se) + b3r);
      sFt[a8*8 + i8] = (_Float16)fr;          // transposed for D's b128 read
    }
    __syncthreads();
    // ---- D (wave-local, dir wv): u_w = sum_i C[wv,i] f_i;
    //      D1_wv = dp1 * (W1 @ u_w), rows l and l+64 via w1a/w1b ----
    {
      uint4 fv = *(const uint4*)&sFt[l*8];    // f_0..7[l], conflict-free
      h2 f01 = __builtin_bit_cast(h2, fv.x);
      h2 f23 = __builtin_bit_cast(h2, fv.y);
      h2 f45 = __builtin_bit_cast(h2, fv.z);
      h2 f67 = __builtin_bit_cast(h2, fv.w);
      float u = cw[0]*(float)f01[0] + cw[1]*(float)f01[1]
              + cw[2]*(float)f23[0] + cw[3]*(float)f23[1]
              + cw[4]*(float)f45[0] + cw[5]*(float)f45[1]
              + cw[6]*(float)f67[0] + cw[7]*(float)f67[1];
      sUw[wv*64 + l] = (_Float16)u;
      asm volatile("s_waitcnt lgkmcnt(0)" ::: "memory");
      const uint4* u4 = (const uint4*)&sUw[wv*64];  // 8 uint4, broadcast
      float a0=0.f, a1=0.f, c0=0.f, c1=0.f;
      #pragma unroll
      for (int q=0; q<8; q++){
        uint4 v = u4[q];
        a0 = dot2(w1a[4*q+0], v.x, a0); a1 = dot2(w1a[4*q+1], v.y, a1);
        a0 = dot2(w1a[4*q+2], v.z, a0); a1 = dot2(w1a[4*q+3], v.w, a1);
        c0 = dot2(w1b[4*q+0], v.x, c0); c1 = dot2(w1b[4*q+1], v.y, c1);
        c0 = dot2(w1b[4*q+2], v.z, c0); c1 = dot2(w1b[4*q+3], v.w, c1);
      }
      sD1[wv*DSTR + l]      = (_Float16)(dp1a*(a0+a1));
      sD1[wv*DSTR + 64 + l] = (_Float16)(dp1b*(c0+c1));
    }
    __syncthreads();
    // ---- E: D2_j = dp2 * (W2 @ D1_j); pair rows, (m,hb) slice ----
    {
      const uint4* d4 = (const uint4*)sD1;
      #pragma unroll
      for (int k=0; k<4; k++){
        const int dir = 4*g + k;
        const uint4* dd = &d4[dir*17 + m*8 + hb*4];
        float e0=0.f, e1=0.f, o0=0.f, o1=0.f;
        #pragma unroll
        for (int q=0; q<4; q++){
          uint4 v = dd[q];
          e0 = dot2(w2h[4*q+0], v.x, e0); e1 = dot2(w2h[4*q+1], v.y, e1);
          e0 = dot2(w2h[4*q+2], v.z, e0); e1 = dot2(w2h[4*q+3], v.w, e1);
          o0 = dot2(w2h[16+4*q+0], v.x, o0); o1 = dot2(w2h[16+4*q+1], v.y, o1);
          o0 = dot2(w2h[16+4*q+2], v.z, o0); o1 = dot2(w2h[16+4*q+3], v.w, o1);
        }
        float zE = dppadd<DPP_ROR8>(e0+e1);
        float zO = dppadd<DPP_ROR8>(o0+o1);
        zE = dppadd<DPP_XOR1>(zE);
        zO = dppadd<DPP_XOR1>(zO);
        float z = hb ? zO : zE;               // own row
        if (m == 0) sD2[dir*DSTR + r] = (_Float16)(dp2*z);
      }
    }
    __syncthreads();
    // ---- F: con = g_i*f + (1-f^2)*(W3 D2_i); k-sum all-DPP; Heun fused ----
    {
      const uint4* d4 = (const uint4*)&sD2[i8*DSTR];
      float e0=0.f, e1=0.f, o0=0.f, o1=0.f;
      #pragma unroll
      for (int q=0; q<8; q++){
        uint4 dv = d4[(a8&1)*8 + q];          // own K-half of D2[i8]
        e0 = dot2(w3e[4*q+0], dv.x, e0); e1 = dot2(w3e[4*q+1], dv.y, e1);
        e0 = dot2(w3e[4*q+2], dv.z, e0); e1 = dot2(w3e[4*q+3], dv.w, e1);
        o0 = dot2(w3o[4*q+0], dv.x, o0); o1 = dot2(w3o[4*q+1], dv.y, o1);
        o0 = dot2(w3o[4*q+2], dv.z, o0); o1 = dot2(w3o[4*q+3], dv.w, o1);
      }
      float ze = dppadd<DPP_ROR8>(e0+e1);
      float zo = dppadd<DPP_ROR8>(o0+o1);
      float z  = (a8&1) ? zo : ze;
      float con = gi*fr + (1.f - fr*fr)*z;
      con = dppadd<DPP_XOR1>(con);            // i8 bit0
      con = dppadd<DPP_XOR2>(con);            // i8 bit1
      con = dppadd<DPP_HMIR>(con);            // i8 bit2 (quad uniform -> l^7 ok)
      if (i8 == 0){
        if (mode == 0){
          sK1[a8] = con;
          sYinp[a8] = (_Float16)(sY[a8] + con);   // midpoint input for eval2
        } else {
          float yn = sY[a8] + 0.5f*(sK1[a8] + con);
          sY[a8] = yn;
          sYinp[a8] = (_Float16)yn;
        }
      }
    }
  };

  // ---- main scan over windows ----
  for (int s = 0; s < NWIN; s++){
    const float* gcur = &sG[s*LSIG];
    gi = gcur[i8];
    // C[wv][i] for this wave's dir (8 uniform LDS reads, per window).
    #pragma unroll
    for (int i=0; i<8; i++){
      if (i == wv) cw[i] = 0.f;
      else {
        int lo = i < wv ? i : wv, hi = i < wv ? wv : i;
        float v = gcur[8 + 7*lo - (lo*(lo-1))/2 + (hi-lo-1)];
        cw[i] = (i < wv) ? v : -v;
      }
    }
    EVAL(0, s);
    EVAL(1, s);
  }
  __syncthreads();
  if (t < 4){                                 // final readout (y after win 31)
    float z = sBr[t] + sSh[0];
    #pragma unroll 8
    for (int a=0; a<64; a++) z += sWr[t*64+a]*sY[a];
    outp[(b*33 + 32)*4 + t] = z;
  }
}

extern "C" void kernel_launch(void* const* d_in, const int* in_sizes, int n_in,
                              void* d_out, int out_size, void* d_ws, size_t ws_size,
                              hipStream_t stream) {
  cde_kernel<<<dim3(NBATCH), dim3(512), 0, stream>>>(
      (const float*)d_in[0],
      (const float*)d_in[1],  (const float*)d_in[2],
      (const float*)d_in[3],  (const float*)d_in[4],
      (const float*)d_in[5],  (const float*)d_in[6],
      (const float*)d_in[7],  (const float*)d_in[8],
      (const float*)d_in[9],  (const float*)d_in[10],
      (const float*)d_in[11], (const float*)d_in[12],
      (const float*)d_in[13],
      (float*)d_out);
}

// Round 7
// 305.001 us; speedup vs baseline: 1.0629x; 1.0607x over previous
//
#include <hip/hip_runtime.h>

// log-ODE Neural CDE. B=32 chains, 32 windows, Heun = 2 vector-field evals
// per window. fp32 in/out, f32 accum, f16 weights/activations (v_dot2_f32_f16).
// 512 threads/block (8 waves), one block per batch element.
//
// R16 = R12 base (233us, VGPR=112, no spill) + VALU-overhead cuts that REDUCE
// register demand. Post-mortem R13-R15: allocator hard-caps VGPR at 128 and
// spills (waves_per_eu inert); R12 VALUBusy => ~1300 VALU instrs/lane/eval vs
// ~370 essential dot2 => ~70% overhead is the target, attacked in-place:
//  * A non-redundant: (m,g)-quarter split, 8 dot2 + XOR1/XOR2 (was 16 dot2 +
//    4 DPP + selects). w1A[8] replaces w1h[16].
//  * D rewrite: per-dir quarter loop reusing w1A (P_i all 8 dirs), combine
//    via per-window sC[8][8] in LDS (built by t<64, ~8 instrs) -- kills the
//    ~100-instr cJ register build. Lane finishes 2 j's: 2 float4 reads+16 fma.
//  * F: last __shfl_xor(4) -> DPP row_half_mirror (quads uniform after
//    XOR1+XOR2): zero LDS ops on the y-update critical path.
#define NBATCH 32
#define LPATH  513
#define NWIN   32
#define LSIG   36
#define DSTR   136   // [dir] stride sD1/sD2 (f16) = 17 uint4
#define FSTR   72    // [dir] stride sFh (f16) = 9 uint4

typedef unsigned int u32;
typedef _Float16 h2 __attribute__((ext_vector_type(2)));

__device__ __forceinline__ u32 pkh(float a, float b){
  return __builtin_bit_cast(u32, __builtin_amdgcn_cvt_pkrtz(a, b));
}
__device__ __forceinline__ float dot2(u32 a, u32 b, float c){
#if __has_builtin(__builtin_amdgcn_fdot2)
  return __builtin_amdgcn_fdot2(__builtin_bit_cast(h2,a),
                                __builtin_bit_cast(h2,b), c, false);
#else
  h2 x = __builtin_bit_cast(h2,a), y = __builtin_bit_cast(h2,b);
  return c + (float)x[0]*(float)y[0] + (float)x[1]*(float)y[1];
#endif
}
__device__ __forceinline__ float tanh_fast(float x){
  float e = __expf(2.f*x);
  return 1.f - 2.f/(e+1.f);
}

// DPP cross-lane adds: VALU-only, no LDS-pipe traffic.
#define DPP_XOR1 0xB1   // quad_perm [1,0,3,2]
#define DPP_XOR2 0x4E   // quad_perm [2,3,0,1]
#define DPP_ROR8 0x128  // row_ror:8 == lane^8 within each 16-lane row
#define DPP_HMIR 0x141  // row_half_mirror == lane^7 within each 8-lane half
template<int CTRL>
__device__ __forceinline__ float dppadd(float x){
  int v = __builtin_amdgcn_update_dpp(0, __builtin_bit_cast(int,x),
                                      CTRL, 0xF, 0xF, false);
  return x + __builtin_bit_cast(float, v);
}

extern "C" __global__ __launch_bounds__(512, 1)
void cde_kernel(const float* __restrict__ cv,
                const float* __restrict__ Wi1g, const float* __restrict__ bi1g,
                const float* __restrict__ Wi2g, const float* __restrict__ bi2g,
                const float* __restrict__ W1g,  const float* __restrict__ b1g,
                const float* __restrict__ W2g,  const float* __restrict__ b2g,
                const float* __restrict__ W3g,  const float* __restrict__ b3g,
                const float* __restrict__ Wrg,  const float* __restrict__ brg,
                const float* __restrict__ shg,
                float* __restrict__ outp)
{
  // ---- LDS (~13 KB) ----
  __shared__ __align__(16) float sG[NWIN*LSIG];
  __shared__ __align__(16) float sWr[256];
  __shared__ float sBr[4], sSh[1];
  __shared__ __align__(16) float sY[64];
  __shared__ float sK1[64], sLw[64];
  __shared__ __align__(16) float sC[64];          // C[j][i] per window
  __shared__ __align__(16) _Float16 sYinp[64];
  __shared__ __align__(16) _Float16 sH1[128];
  __shared__ __align__(16) _Float16 sH2[128];
  __shared__ __align__(16) _Float16 sFh[8*FSTR];
  __shared__ __align__(16) _Float16 sD1[8*DSTR];
  __shared__ __align__(16) _Float16 sD2[8*DSTR];

  const int t  = threadIdx.x;        // 0..511
  const int b  = blockIdx.x;
  const int r  = t >> 2;             // 0..127 (A/B/D/E row)
  const int m  = t & 1;              // K quarter bit 0
  const int g  = (t >> 1) & 1;       // K quarter bit 1 / dir group (E)
  const int hb = (t >> 3) & 1;       // bit3: pair K-slice selector (B/E)
  const int i8 = t & 7;              // dir (C/F row-block)
  const int a8 = t >> 3;             // 0..63 (C/F col within block)
  const int p  = i8*64 + a8;         // owned W3 row
  const int pE = i8*64 + (a8 & ~1);  // C/F pair's even row
  const int pO = i8*64 + (a8 |  1);  // C/F pair's odd row
  const int rE = r & ~2;             // B/E pair's even row
  const int rO = r |  2;             // B/E pair's odd row

  // ---- init readout consts ----
  if (t < 256) sWr[t] = Wrg[t];
  if (t < 4)   sBr[t] = brg[t];
  if (t == 0)  sSh[0] = shg[0];

  // ---- depth-2 Lyndon log-signatures, one window per thread (t<32) ----
  if (t < NWIN){
    const float4* cv4 = (const float4*)cv;
    const int base = (b*LPATH + t*16)*2;
    float cur[8], pre[8], acc[8], lvw[28];
    { float4 a = cv4[base], d = cv4[base+1];
      cur[0]=a.x;cur[1]=a.y;cur[2]=a.z;cur[3]=a.w;
      cur[4]=d.x;cur[5]=d.y;cur[6]=d.z;cur[7]=d.w; }
    #pragma unroll
    for (int d=0; d<8; d++){ pre[d]=0.f; acc[d]=0.f; }
    #pragma unroll
    for (int pq=0; pq<28; pq++) lvw[pq]=0.f;
    for (int w=1; w<=16; w++){
      float nxt[8], inc[8];
      { float4 a = cv4[base+2*w], d = cv4[base+2*w+1];
        nxt[0]=a.x;nxt[1]=a.y;nxt[2]=a.z;nxt[3]=a.w;
        nxt[4]=d.x;nxt[5]=d.y;nxt[6]=d.z;nxt[7]=d.w; }
      #pragma unroll
      for (int d=0; d<8; d++) inc[d] = nxt[d]-cur[d];
      int pq=0;
      #pragma unroll
      for (int i=0; i<8; i++)
        #pragma unroll
        for (int j2=i+1; j2<8; j2++){ lvw[pq] += pre[i]*inc[j2] - pre[j2]*inc[i]; pq++; }
      #pragma unroll
      for (int d=0; d<8; d++){ acc[d]+=inc[d]; pre[d]+=inc[d]; cur[d]=nxt[d]; }
    }
    float* gd = &sG[t*LSIG];
    #pragma unroll
    for (int d=0; d<8; d++) gd[d] = acc[d];
    #pragma unroll
    for (int pq=0; pq<28; pq++) gd[8+pq] = 0.5f*lvw[pq];
  }

  // ---- y0 = Wi2 @ lipswish(Wi1 @ x0 + bi1) + bi2 ----
  if (t < 64){
    float z = bi1g[t];
    #pragma unroll
    for (int d=0; d<8; d++) z += Wi1g[t*8+d] * cv[(b*LPATH)*8 + d];
    float s = 1.f/(1.f+__expf(-z));
    sLw[t] = 0.909f*z*s;
  }
  __syncthreads();
  if (t < 64){
    float z = bi2g[t];
    #pragma unroll 8
    for (int k=0; k<64; k++) z += Wi2g[t*64+k] * sLw[k];
    sY[t] = z;
    sYinp[t] = (_Float16)z;
  }
  __syncthreads();
  if (t < 4){
    float z = sBr[t] + sSh[0];
    #pragma unroll 8
    for (int a=0; a<64; a++) z += sWr[t*64+a]*sY[a];
    outp[(b*33 + 0)*4 + t] = z;
  }

  // ---- per-thread weight registers ----
  // w1A: (m,g)-quarter (16 cols) of W1 row r  -> A and D.
  // w2h: (m,hb)-slice of W2 rows rE/rO        -> B and E (R12 layout).
  // w3e/w3o: K-half (a8&1) of rows pE/pO      -> C and F (pair-split).
  u32 w1A[8], w2h[32], w3e[32], w3o[32];
  {
    const float2* W1f2 = (const float2*)W1g;
    #pragma unroll
    for (int i=0; i<8; i++){ float2 v = W1f2[r*32 + m*16 + g*8 + i]; w1A[i] = pkh(v.x, v.y); }
    const float2* W2f2 = (const float2*)W2g;
    #pragma unroll
    for (int i=0; i<16; i++){ float2 v = W2f2[rE*64 + m*32 + hb*16 + i]; w2h[i]    = pkh(v.x, v.y); }
    #pragma unroll
    for (int i=0; i<16; i++){ float2 v = W2f2[rO*64 + m*32 + hb*16 + i]; w2h[16+i] = pkh(v.x, v.y); }
    const float4* W3f4 = (const float4*)W3g;
    #pragma unroll
    for (int k=0; k<16; k++){
      float4 v = W3f4[pE*32 + (a8&1)*16 + k];
      w3e[2*k]   = pkh(v.x, v.y);
      w3e[2*k+1] = pkh(v.z, v.w);
    }
    #pragma unroll
    for (int k=0; k<16; k++){
      float4 v = W3f4[pO*32 + (a8&1)*16 + k];
      w3o[2*k]   = pkh(v.x, v.y);
      w3o[2*k+1] = pkh(v.z, v.w);
    }
  }
  const float b1r = b1g[r], b2r = b2g[r], b3r = b3g[p];

  float gi = 0.f;       // gcur[i8], per window

  // One vector-field eval. mode 0: k1 (sK1, sYinp=y+k1, fused readout in A).
  // mode 1: k2 (Heun update fused in F).
  auto EVAL = [&](int mode, int s){
    __syncthreads();                          // sYinp (and sY, sC) ready
    float dp1, dp2, fr;
    // ---- A: h1 = lipswish(W1 y + b1); (m,g) quarter, non-redundant ----
    {
      if (mode == 0 && s > 0 && t >= 504 && t < 508){
        int o = t - 504;
        float z = sBr[o] + sSh[0];
        const float4* wr4 = (const float4*)&sWr[o*64];
        const float4* y4f = (const float4*)sY;
        #pragma unroll
        for (int q=0; q<16; q++){
          float4 w = wr4[q], y = y4f[q];
          z += w.x*y.x + w.y*y.y + w.z*y.z + w.w*y.w;
        }
        outp[(b*33 + s)*4 + o] = z;
      }
      const uint4* y4 = (const uint4*)sYinp;
      const int qa = m*4 + g*2;               // own quarter: 2 uint4
      uint4 A0 = y4[qa], A1 = y4[qa+1];
      float z0 = dot2(w1A[0], A0.x, 0.f), z1 = dot2(w1A[1], A0.y, 0.f);
      z0 = dot2(w1A[2], A0.z, z0); z1 = dot2(w1A[3], A0.w, z1);
      z0 = dot2(w1A[4], A1.x, z0); z1 = dot2(w1A[5], A1.y, z1);
      z0 = dot2(w1A[6], A1.z, z0); z1 = dot2(w1A[7], A1.w, z1);
      float z = z0 + z1;
      z = dppadd<DPP_XOR1>(z);                // sum m quarters
      z = dppadd<DPP_XOR2>(z);                // sum g quarters
      z += b1r;
      float sg = 1.f/(1.f+__expf(-z));
      dp1 = 0.909f*sg*(1.f + z*(1.f-sg));
      if ((t & 3) == 0) sH1[r] = (_Float16)(0.909f*z*sg);
    }
    __syncthreads();
    // ---- B: h2 = lipswish(W2 h1 + b2); pair rows, (m,hb) slice ----
    {
      const uint4* h4 = (const uint4*)sH1;
      const int qb = m*8 + hb*4;              // (m*64+hb*32)/8
      float e0=0.f, e1=0.f, o0=0.f, o1=0.f;
      #pragma unroll
      for (int q=0; q<4; q++){
        uint4 v = h4[qb + q];
        e0 = dot2(w2h[4*q+0], v.x, e0); e1 = dot2(w2h[4*q+1], v.y, e1);
        e0 = dot2(w2h[4*q+2], v.z, e0); e1 = dot2(w2h[4*q+3], v.w, e1);
        o0 = dot2(w2h[16+4*q+0], v.x, o0); o1 = dot2(w2h[16+4*q+1], v.y, o1);
        o0 = dot2(w2h[16+4*q+2], v.z, o0); o1 = dot2(w2h[16+4*q+3], v.w, o1);
      }
      float zE = dppadd<DPP_ROR8>(e0+e1);
      float zO = dppadd<DPP_ROR8>(o0+o1);
      zE = dppadd<DPP_XOR1>(zE);
      zO = dppadd<DPP_XOR1>(zO);
      float z = (hb ? zO : zE) + b2r;
      float sg = 1.f/(1.f+__expf(-z));
      dp2 = 0.909f*sg*(1.f + z*(1.f-sg));
      if ((t & 3) == 0) sH2[r] = (_Float16)(0.909f*z*sg);
    }
    __syncthreads();
    // ---- C: f = tanh(W3 h2 + b3); pair-split K-halves ----
    {
      const uint4* h4 = (const uint4*)sH2;
      float e0=0.f, e1=0.f, o0=0.f, o1=0.f;
      #pragma unroll
      for (int q=0; q<8; q++){
        uint4 hv = h4[(a8&1)*8 + q];          // own K-half only (8 uint4)
        e0 = dot2(w3e[4*q+0], hv.x, e0); e1 = dot2(w3e[4*q+1], hv.y, e1);
        e0 = dot2(w3e[4*q+2], hv.z, e0); e1 = dot2(w3e[4*q+3], hv.w, e1);
        o0 = dot2(w3o[4*q+0], hv.x, o0); o1 = dot2(w3o[4*q+1], hv.y, o1);
        o0 = dot2(w3o[4*q+2], hv.z, o0); o1 = dot2(w3o[4*q+3], hv.w, o1);
      }
      float se = dppadd<DPP_ROR8>(e0+e1);     // + partner's other-half partial
      float so = dppadd<DPP_ROR8>(o0+o1);
      fr = tanh_fast(((a8&1) ? so : se) + b3r);
      sFh[i8*FSTR + a8] = (_Float16)fr;
    }
    __syncthreads();
    // ---- D: P_i = W1 @ f_i (all 8 dirs, (m,g) quarter + XOR1/XOR2);
    //      D1_j[r] = dp1 * sum_i C[j,i] P_i for this lane's 2 j's (sC) ----
    {
      const uint4* f4 = (const uint4*)sFh;
      const int qo = m*4 + g*2;               // quarter offset in uint4
      float P[8];
      #pragma unroll
      for (int i=0; i<8; i++){
        const uint4* fd = &f4[i*9 + qo];
        uint4 A0 = fd[0], A1 = fd[1];
        float z0 = dot2(w1A[0], A0.x, 0.f), z1 = dot2(w1A[1], A0.y, 0.f);
        z0 = dot2(w1A[2], A0.z, z0); z1 = dot2(w1A[3], A0.w, z1);
        z0 = dot2(w1A[4], A1.x, z0); z1 = dot2(w1A[5], A1.y, z1);
        z0 = dot2(w1A[6], A1.z, z0); z1 = dot2(w1A[7], A1.w, z1);
        float pz = z0 + z1;
        pz = dppadd<DPP_XOR1>(pz);
        pz = dppadd<DPP_XOR2>(pz);
        P[i] = pz;                            // full P_i[r] on all 4 lanes
      }
      const int jb = 4*g + 2*m;               // this lane's 2 j's: jb, jb+1
      const float4* c4 = (const float4*)sC;
      #pragma unroll
      for (int jj=0; jj<2; jj++){
        const int j = jb + jj;
        float4 cA = c4[j*2], cB = c4[j*2+1];
        float pj = cA.x*P[0] + cA.y*P[1] + cA.z*P[2] + cA.w*P[3]
                 + cB.x*P[4] + cB.y*P[5] + cB.z*P[6] + cB.w*P[7];
        sD1[j*DSTR + r] = (_Float16)(dp1*pj);
      }
    }
    __syncthreads();
    // ---- E: D2_j = dp2 * (W2 @ D1_j); pair rows, (m,hb) slice ----
    {
      const uint4* d4 = (const uint4*)sD1;
      #pragma unroll
      for (int k=0; k<4; k++){
        const int dir = 4*g + k;
        const uint4* dd = &d4[dir*17 + m*8 + hb*4];
        float e0=0.f, e1=0.f, o0=0.f, o1=0.f;
        #pragma unroll
        for (int q=0; q<4; q++){
          uint4 v = dd[q];
          e0 = dot2(w2h[4*q+0], v.x, e0); e1 = dot2(w2h[4*q+1], v.y, e1);
          e0 = dot2(w2h[4*q+2], v.z, e0); e1 = dot2(w2h[4*q+3], v.w, e1);
          o0 = dot2(w2h[16+4*q+0], v.x, o0); o1 = dot2(w2h[16+4*q+1], v.y, o1);
          o0 = dot2(w2h[16+4*q+2], v.z, o0); o1 = dot2(w2h[16+4*q+3], v.w, o1);
        }
        float zE = dppadd<DPP_ROR8>(e0+e1);
        float zO = dppadd<DPP_ROR8>(o0+o1);
        zE = dppadd<DPP_XOR1>(zE);
        zO = dppadd<DPP_XOR1>(zO);
        float z = hb ? zO : zE;               // own row
        if (m == 0) sD2[dir*DSTR + r] = (_Float16)(dp2*z);
      }
    }
    __syncthreads();
    // ---- F: con = g_i*f + (1-f^2)*(W3 D2_i); k-sum all-DPP; Heun fused ----
    {
      const uint4* d4 = (const uint4*)&sD2[i8*DSTR];
      float e0=0.f, e1=0.f, o0=0.f, o1=0.f;
      #pragma unroll
      for (int q=0; q<8; q++){
        uint4 dv = d4[(a8&1)*8 + q];          // own K-half of D2[i8]
        e0 = dot2(w3e[4*q+0], dv.x, e0); e1 = dot2(w3e[4*q+1], dv.y, e1);
        e0 = dot2(w3e[4*q+2], dv.z, e0); e1 = dot2(w3e[4*q+3], dv.w, e1);
        o0 = dot2(w3o[4*q+0], dv.x, o0); o1 = dot2(w3o[4*q+1], dv.y, o1);
        o0 = dot2(w3o[4*q+2], dv.z, o0); o1 = dot2(w3o[4*q+3], dv.w, o1);
      }
      float ze = dppadd<DPP_ROR8>(e0+e1);
      float zo = dppadd<DPP_ROR8>(o0+o1);
      float z  = (a8&1) ? zo : ze;
      float con = gi*fr + (1.f - fr*fr)*z;
      con = dppadd<DPP_XOR1>(con);            // i8 bit0
      con = dppadd<DPP_XOR2>(con);            // i8 bit1
      con = dppadd<DPP_HMIR>(con);            // i8 bit2 (quad uniform -> l^7 ok)
      if (i8 == 0){
        if (mode == 0){
          sK1[a8] = con;
          sYinp[a8] = (_Float16)(sY[a8] + con);   // midpoint input for eval2
        } else {
          float yn = sY[a8] + 0.5f*(sK1[a8] + con);
          sY[a8] = yn;
          sYinp[a8] = (_Float16)yn;
        }
      }
    }
  };

  // ---- main scan over windows ----
  for (int s = 0; s < NWIN; s++){
    const float* gcur = &sG[s*LSIG];
    gi = gcur[i8];
    // build antisymmetric C[j][i] in LDS (t<64, ~8 instrs; replaces cJ regs).
    // Safe: prev EVAL's sC reads are >=1 barrier old; F doesn't touch sC;
    // EVAL(0)'s top __syncthreads publishes before D reads.
    if (t < 64){
      const int j = t >> 3, i = t & 7;
      float v = 0.f;
      if (i < j)      v =  gcur[8 + 7*i - (i*(i-1))/2 + (j-i-1)];
      else if (i > j) v = -gcur[8 + 7*j - (j*(j-1))/2 + (i-j-1)];
      sC[j*8 + i] = v;
    }
    EVAL(0, s);
    EVAL(1, s);
  }
  __syncthreads();
  if (t < 4){                                 // final readout (y after win 31)
    float z = sBr[t] + sSh[0];
    #pragma unroll 8
    for (int a=0; a<64; a++) z += sWr[t*64+a]*sY[a];
    outp[(b*33 + 32)*4 + t] = z;
  }
}

extern "C" void kernel_launch(void* const* d_in, const int* in_sizes, int n_in,
                              void* d_out, int out_size, void* d_ws, size_t ws_size,
                              hipStream_t stream) {
  cde_kernel<<<dim3(NBATCH), dim3(512), 0, stream>>>(
      (const float*)d_in[0],
      (const float*)d_in[1],  (const float*)d_in[2],
      (const float*)d_in[3],  (const float*)d_in[4],
      (const float*)d_in[5],  (const float*)d_in[6],
      (const float*)d_in[7],  (const float*)d_in[8],
      (const float*)d_in[9],  (const float*)d_in[10],
      (const float*)d_in[11], (const float*)d_in[12],
      (const float*)d_in[13],
      (float*)d_out);
}